// Round 10
// baseline (551.118 us; speedup 1.0000x reference)
//
#include <hip/hip_runtime.h>

typedef unsigned short u16;
typedef unsigned int u32;
typedef unsigned char u8t;
using bfrag = __attribute__((ext_vector_type(8))) short;   // 8 x bf16 (raw bits)
using facc  = __attribute__((ext_vector_type(4))) float;   // MFMA accumulator

// ---------------- numeric helpers ----------------
__device__ __forceinline__ u16 f2b(float f) {              // f32 -> bf16 (RNE)
  u32 u = __float_as_uint(f);
  return (u16)((u + 0x7FFFu + ((u >> 16) & 1u)) >> 16);
}
__device__ __forceinline__ float b2f(u16 h) { return __uint_as_float(((u32)h) << 16); }
__device__ __forceinline__ u32 encf(float f) {             // order-preserving f32->u32
  u32 u = __float_as_uint(f);
  return (u & 0x80000000u) ? ~u : (u | 0x80000000u);
}
__device__ __forceinline__ float decf(u32 e) {
  return __uint_as_float((e & 0x80000000u) ? (e & 0x7FFFFFFFu) : ~e);
}
// branchless mish: v*tanh(softplus(v)) = v - 2v/(e^v(e^v+2)+2)
__device__ __forceinline__ float mish_f(float v) {
  float ev = __expf(v);
  float d = __builtin_fmaf(ev, ev + 2.f, 2.f);
  return __builtin_fmaf(-2.f * v, __builtin_amdgcn_rcpf(d), v);
}
__device__ __forceinline__ float ldf(const void* p, int i, int bf) {
  return bf ? b2f(((const u16*)p)[i]) : ((const float*)p)[i];
}
__device__ __forceinline__ u8t f2fp8(float f) {            // f32 -> fp8 e4m3 (OCP)
  return (u8t)(__builtin_amdgcn_cvt_pk_fp8_f32(f, f, 0, 0) & 0xFF);
}
// fp8 LDS tile: row stride 256B, XOR swizzle bits 4..6
__device__ __forceinline__ char* tp8(char* base, int row, int colb) {
  return base + ((row << 8) + (colb ^ ((row & 7) << 4)));
}

// ---------------- dtype detector ----------------
__global__ void detect_dtype_kernel(const void* __restrict__ x, int* __restrict__ flag) {
  __shared__ int cnt;
  const int tid = threadIdx.x;
  if (tid == 0) cnt = 0;
  __syncthreads();
  const u16* p = (const u16*)x;
  u16 h = p[tid * 96 + 4];
  int e = (int)((h >> 7) & 0xFF);
  if (e >= 116 && e <= 134) atomicAdd(&cnt, 1);
  __syncthreads();
  if (tid == 0) *flag = (cnt >= 128) ? 1 : 0;
}

// ---------------- consolidated prep (523 blocks, 256 thr) ----------------
// bid<256: W_embed col-tiles -> Wt8 ; bid<512: Wqk -> Wqk8 ; bid<519: dqkp8 ;
// bid==519: dqc ; bid==520: unused ; bid==521: invP ; bid==522: uvw_tl tiles
__global__ void prep_all(const void* __restrict__ W_embed,
                         const void* __restrict__ Wq, const void* __restrict__ Wk,
                         const void* __restrict__ bq, const void* __restrict__ bk,
                         const void* __restrict__ dq,
                         const int* __restrict__ vi, const int* __restrict__ pi,
                         const int* __restrict__ qi, const int* __restrict__ qpi,
                         int nv, int np,
                         u8t* __restrict__ Wt8, u8t* __restrict__ Wqk8,
                         u8t* __restrict__ dqkp8, u8t* __restrict__ uvw_tl,
                         float* __restrict__ dqc,
                         u32* __restrict__ invP, const int* __restrict__ dflag) {
  __shared__ float wkrow[256];
  __shared__ u16 wqt[64][260];
  const int bid = blockIdx.x;
  const int bf = *dflag;
  const int t = threadIdx.x;

  if (bid < 256) {                 // ---- Wt8 tiles ----
    const int k = bid, n = t;
    u8t v = f2fp8(ldf(W_embed, (k << 8) + n, bf));
    int nt = n >> 4, lr = n & 15, kt = k >> 5, lg = (k >> 3) & 3, e = k & 7;
    Wt8[(((nt << 3) + kt) << 9) + (((lg << 4) + lr) << 3) + e] = v;
  } else if (bid < 512) {          // ---- Wqk8 tiles ----
    const int n = bid - 256, k = t;
    wkrow[k] = ldf(Wk, (n << 8) + k, bf);
    float s = 0.f;
    for (int d0 = 0; d0 < 256; d0 += 64) {
      __syncthreads();
      for (int it = 0; it < 64; ++it) {
        int kk = (it << 2) + (t >> 6);
        int dd = t & 63;
        wqt[dd][kk] = f2b(ldf(Wq, (kk << 8) + d0 + dd, bf));
      }
      __syncthreads();
      #pragma unroll 8
      for (int dd = 0; dd < 64; ++dd) s += b2f(wqt[dd][k]) * wkrow[d0 + dd];
    }
    int nt = n >> 4, lr = n & 15, kt = k >> 5, lg = (k >> 3) & 3, e = k & 7;
    Wqk8[(((nt << 3) + kt) << 9) + (((lg << 4) + lr) << 3) + e] = f2fp8(s);
  } else if (bid < 519) {          // ---- dqkp rows ----
    const int blk = bid - 512, d = t;
    float s = 0.f;
    for (int nn = 0; nn < 256; ++nn)
      s += ldf(Wk, (d << 8) + nn, bf) * ldf(dq, (blk << 8) + nn, bf);
    dqkp8[(blk << 8) + d] = f2fp8(s);
  } else if (bid == 519) {         // ---- dqc ----
    if (t < 7) {
      float s = 0.f;
      for (int nn = 0; nn < 256; ++nn) s += ldf(dq, (t << 8) + nn, bf) * ldf(bk, nn, bf);
      dqc[t] = s;
    } else if (t == 7) {
      float s = 0.f;
      for (int nn = 0; nn < 256; ++nn) s += ldf(bq, nn, bf) * ldf(bk, nn, bf);
      dqc[7] = s;
    }
  } else if (bid == 521) {         // ---- invP ----
    for (int i = t; i < 6561; i += 256) invP[i] = 0u;
    __syncthreads();
    for (int i = t; i < nv; i += 256) atomicOr(&invP[vi[i]], (u32)(pi[i] + 1));
    for (int i = t; i < np; i += 256) atomicOr(&invP[qi[i]], ((u32)(qpi[i] + 1)) << 16);
  } else if (bid == 522) {         // ---- uvw A-fragment tiles (row0=u=Wq@bk, row1=w=Wk@bq) ----
    for (int s = t; s < 512; s += 256) {
      int kt = s >> 6, ln = s & 63, lr2 = ln & 15, lg2 = ln >> 4;
      #pragma unroll 1
      for (int e = 0; e < 8; ++e) {
        float v = 0.f;
        if (lr2 < 2) {
          int k = kt * 32 + lg2 * 8 + e;
          const void* M = (lr2 == 0) ? Wq : Wk;
          const void* bv = (lr2 == 0) ? bk : bq;
          for (int nn = 0; nn < 256; ++nn)
            v += ldf(M, (k << 8) + nn, bf) * ldf(bv, nn, bf);
        }
        uvw_tl[(s << 3) + e] = f2fp8(v);
      }
    }
  }
}

// ---------------- fused kernel: 256 thr, 1 element/block, 3 blocks/CU ----------------
// LDS (52864 B, 3x = 158592 <= 160K):
//   bufA @0      [88][256] fp8 swz  (x rows 0..80 -> T; rows 81..87 = dqkp)
//   bufP @22528  [81][256] fp8 swz  (pe)  [frag reads of rows 81..95 spill into pol
//                                          region -> garbage feeding DISCARDED rows/cols]
//   pol  @43264  [2187] u32
//   alpha@52012 [96] f32 ; beta@52396 [96] f32 ; dqcS@52780 [8] f32
#define LDS_TOTAL 52864

// (256,3): 3 waves/EU. Allocator splits unified file evenly (84 arch + 84 acc of 168)
// when AGPRs are in use -> keep AGPR peak <= 24 (one acc set at a time, unroll 1 on
// pass loops) and arch bursts small (staging unroll 2) so neither side exceeds 84.
__global__ __launch_bounds__(256, 3)
void dirpolicy_fp8(const void* __restrict__ x,
                   const void* __restrict__ b_embed,
                   const u8t* __restrict__ Wt8,
                   const u8t* __restrict__ Wqk8,
                   const u8t* __restrict__ dqkp8,
                   const u8t* __restrict__ uvw_tl,
                   const float* __restrict__ dqc,
                   const u32* __restrict__ invP,
                   void* __restrict__ out,
                   const int* __restrict__ dflag) {
  extern __shared__ char smem[];
  char* bufA = smem;
  char* bufP = smem + 22528;
  u32* pol = (u32*)(smem + 43264);
  float* alpha = (float*)(smem + 52012);
  float* beta  = (float*)(smem + 52396);
  float* dqcS  = (float*)(smem + 52780);

  const int tid = threadIdx.x;
  const int lane = tid & 63;
  const int w = tid >> 6;          // wave 0..3
  const int lr = lane & 15;
  const int lg = lane >> 4;
  const int isbf = *dflag;
  const int b = blockIdx.x;
  const u32 ENEG = encf(-1e10f);

  // ---- prologue: consts + pol init ----
  for (int i = tid; i < 1792; i += 256) {      // bufA rows 81..87 = dqkp
    int q = i >> 8, d = i & 255;
    *tp8(bufA, 81 + q, d) = dqkp8[i];
  }
  for (int i = tid; i < 2187; i += 256) pol[i] = ENEG;
  if (tid < 8) dqcS[tid] = dqc[tid];

  // ---- stage x -> bufA rows 0..80 (fp8); unroll 2 keeps load burst small ----
  if (isbf) {
    const u16* xb = (const u16*)x + (size_t)b * 20736u;
    #pragma unroll 2
    for (int c = 0; c < 11; ++c) {
      int idx = tid + (c << 8);
      if (idx < 2592) {
        bfrag v = *(const bfrag*)(xb + (idx << 3));
        u32 lo = __builtin_amdgcn_cvt_pk_fp8_f32(b2f((u16)v[0]), b2f((u16)v[1]), 0, 0);
        lo = __builtin_amdgcn_cvt_pk_fp8_f32(b2f((u16)v[2]), b2f((u16)v[3]), lo, 1);
        u32 hi = __builtin_amdgcn_cvt_pk_fp8_f32(b2f((u16)v[4]), b2f((u16)v[5]), 0, 0);
        hi = __builtin_amdgcn_cvt_pk_fp8_f32(b2f((u16)v[6]), b2f((u16)v[7]), hi, 1);
        uint2 pk; pk.x = lo; pk.y = hi;
        *(uint2*)tp8(bufA, idx >> 5, (idx & 31) << 3) = pk;
      }
    }
  } else {
    const float4* xs = (const float4*)((const float*)x + (size_t)b * 20736u);
    #pragma unroll 2
    for (int c = 0; c < 11; ++c) {
      int idx = tid + (c << 8);
      if (idx < 2592) {
        float4 p0 = xs[idx * 2], p1 = xs[idx * 2 + 1];
        u32 lo = __builtin_amdgcn_cvt_pk_fp8_f32(p0.x, p0.y, 0, 0);
        lo = __builtin_amdgcn_cvt_pk_fp8_f32(p0.z, p0.w, lo, 1);
        u32 hi = __builtin_amdgcn_cvt_pk_fp8_f32(p1.x, p1.y, 0, 0);
        hi = __builtin_amdgcn_cvt_pk_fp8_f32(p1.z, p1.w, hi, 1);
        uint2 pk; pk.x = lo; pk.y = hi;
        *(uint2*)tp8(bufA, idx >> 5, (idx & 31) << 3) = pk;
      }
    }
  }
  __syncthreads();   // bar0: x + consts + pol staged

  // ===== phase 1: pe = mish(x @ We + b) -> bufP; 4 sequential acc[3][2] passes =====
  #pragma unroll 1
  for (int rh = 0; rh < 2; ++rh) {
    #pragma unroll 1
    for (int jh = 0; jh < 2; ++jh) {
      facc acc[3][2];
      facc z4 = {0.f, 0.f, 0.f, 0.f};
      #pragma unroll
      for (int i = 0; i < 3; ++i)
        #pragma unroll
        for (int jj = 0; jj < 2; ++jj) acc[i][jj] = z4;
      #pragma unroll
      for (int kt = 0; kt < 8; ++kt) {
        long bb[2], a[3];
        #pragma unroll
        for (int jj = 0; jj < 2; ++jj)
          bb[jj] = *(const long*)(Wt8 + (((((w << 2) + (jh << 1) + jj) << 3) + kt) << 9) + (lane << 3));
        #pragma unroll
        for (int i = 0; i < 3; ++i)
          a[i] = *(const long*)tp8(bufA, rh * 48 + i * 16 + lr, (kt << 5) + (lg << 3));
        #pragma unroll
        for (int i = 0; i < 3; ++i)
          #pragma unroll
          for (int jj = 0; jj < 2; ++jj)
            acc[i][jj] = __builtin_amdgcn_mfma_f32_16x16x32_fp8_fp8(a[i], bb[jj], acc[i][jj], 0, 0, 0);
      }
      #pragma unroll
      for (int jj = 0; jj < 2; ++jj) {
        const int col = (w << 6) + ((jh << 1) + jj) * 16 + lr;
        const float bias = ldf(b_embed, col, isbf);
        #pragma unroll
        for (int i = 0; i < 3; ++i)
          #pragma unroll
          for (int r = 0; r < 4; ++r) {
            const int row = rh * 48 + i * 16 + (lg << 2) + r;
            if (row < 81)
              *tp8(bufP, row, col) = f2fp8(mish_f(acc[i][jj][r] + bias));
          }
      }
    }
  }
  __syncthreads();   // bar1: pe complete; bufA rows<81 free

  // ===== mini-GEMM: alpha/beta = [u;w] @ pe^T (waves 0..2, 8 AGPR) =====
  if (w < 3) {
    facc ae0, ae1;
    {
      facc z4 = {0.f, 0.f, 0.f, 0.f};
      ae0 = z4; ae1 = z4;
    }
    #pragma unroll
    for (int kt = 0; kt < 8; ++kt) {
      long av = *(const long*)(uvw_tl + (kt << 9) + (lane << 3));
      long b0 = *(const long*)tp8(bufP, (w << 5) + lr, (kt << 5) + (lg << 3));
      long b1 = *(const long*)tp8(bufP, (w << 5) + 16 + lr, (kt << 5) + (lg << 3));
      ae0 = __builtin_amdgcn_mfma_f32_16x16x32_fp8_fp8(av, b0, ae0, 0, 0, 0);
      ae1 = __builtin_amdgcn_mfma_f32_16x16x32_fp8_fp8(av, b1, ae1, 0, 0, 0);
    }
    if (lg == 0) {                    // C rows 0 (u-dot) and 1 (w-dot) live in lg==0, r=0/1
      const float c7 = dqcS[7];
      const int col0 = (w << 5) + lr, col1 = col0 + 16;
      if (col0 < 81) { alpha[col0] = (ae0[0] + c7) * 0.0625f; beta[col0] = ae0[1] * 0.0625f; }
      if (col1 < 81) { alpha[col1] = (ae1[0] + c7) * 0.0625f; beta[col1] = ae1[1] * 0.0625f; }
    }
  }

  // ===== phase 3: T = pe @ Wqk -> bufA rows 0..80; 4 sequential passes =====
  #pragma unroll 1
  for (int rh = 0; rh < 2; ++rh) {
    #pragma unroll 1
    for (int jh = 0; jh < 2; ++jh) {
      facc acc2[3][2];
      facc z4 = {0.f, 0.f, 0.f, 0.f};
      #pragma unroll
      for (int i = 0; i < 3; ++i)
        #pragma unroll
        for (int jj = 0; jj < 2; ++jj) acc2[i][jj] = z4;
      #pragma unroll
      for (int kt = 0; kt < 8; ++kt) {
        long bb[2], a[3];
        #pragma unroll
        for (int jj = 0; jj < 2; ++jj)
          bb[jj] = *(const long*)(Wqk8 + (((((w << 2) + (jh << 1) + jj) << 3) + kt) << 9) + (lane << 3));
        #pragma unroll
        for (int i = 0; i < 3; ++i)
          a[i] = *(const long*)tp8(bufP, rh * 48 + i * 16 + lr, (kt << 5) + (lg << 3));
        #pragma unroll
        for (int i = 0; i < 3; ++i)
          #pragma unroll
          for (int jj = 0; jj < 2; ++jj)
            acc2[i][jj] = __builtin_amdgcn_mfma_f32_16x16x32_fp8_fp8(a[i], bb[jj], acc2[i][jj], 0, 0, 0);
      }
      #pragma unroll
      for (int jj = 0; jj < 2; ++jj) {
        const int col = (w << 6) + ((jh << 1) + jj) * 16 + lr;
        #pragma unroll
        for (int i = 0; i < 3; ++i)
          #pragma unroll
          for (int r = 0; r < 4; ++r) {
            const int row = rh * 48 + i * 16 + (lg << 2) + r;
            if (row < 81) *tp8(bufA, row, col) = f2fp8(acc2[i][jj][r]);
          }
      }
    }
  }
  __syncthreads();   // bar2: T + alpha/beta visible

  // ===== phase 4: board = [T;dqkp] @ pe^T, 2x2 wave grid, two column passes;
  //       scatter each pass straight from its accumulators (<=24 AGPR live) =====
  const int wr4 = w >> 1;          // rows wr4*48..+47
  const int wc4 = w & 1;           // cols wc4*48..+47
  #pragma unroll 1
  for (int pass = 0; pass < 2; ++pass) {
    const int nj = pass ? 1 : 2;
    const int jb = pass ? 2 : 0;
    facc bd[3][2];
    {
      facc z4 = {0.f, 0.f, 0.f, 0.f};
      #pragma unroll
      for (int i = 0; i < 3; ++i)
        #pragma unroll
        for (int jj = 0; jj < 2; ++jj) bd[i][jj] = z4;
    }
    #pragma unroll
    for (int kt = 0; kt < 8; ++kt) {
      long a[3], bb[2];
      #pragma unroll
      for (int i = 0; i < 3; ++i)
        a[i] = *(const long*)tp8(bufA, wr4 * 48 + i * 16 + lr, (kt << 5) + (lg << 3));
      #pragma unroll
      for (int jj = 0; jj < 2; ++jj)
        bb[jj] = (jj < nj)
          ? *(const long*)tp8(bufP, wc4 * 48 + (jb + jj) * 16 + lr, (kt << 5) + (lg << 3))
          : 0L;
      #pragma unroll
      for (int i = 0; i < 3; ++i)
        #pragma unroll
        for (int jj = 0; jj < 2; ++jj)
          if (jj < nj)
            bd[i][jj] = __builtin_amdgcn_mfma_f32_16x16x32_fp8_fp8(a[i], bb[jj], bd[i][jj], 0, 0, 0);
    }
    // scatter this pass (alpha/beta ready since bar2; pol inited at prologue)
    #pragma unroll
    for (int jj = 0; jj < 2; ++jj) {
      if (jj >= nj) continue;
      const int colb = wc4 * 48 + (jb + jj) * 16 + lr;
      const float betv = (colb < 81) ? beta[colb] : 0.f;
      #pragma unroll
      for (int i = 0; i < 3; ++i)
        #pragma unroll
        for (int r = 0; r < 4; ++r) {
          const int rowb = wr4 * 48 + i * 16 + (lg << 2) + r;
          if (rowb < 81) {
            if (colb < 81) {
              const u32 ev = encf(bd[i][jj][r] * 0.0625f + alpha[rowb] + betv);
              const u32 pv = invP[rowb * 81 + colb];
              if (pv & 0xFFFFu) atomicMax(&pol[(pv & 0xFFFFu) - 1], ev);
              if (pv >> 16)     atomicMax(&pol[(pv >> 16) - 1], ev);
            }
          } else if (rowb < 88 && colb < 81) {
            pol[1620 + (rowb - 81) * 81 + colb] =
                encf((bd[i][jj][r] + dqcS[rowb - 81]) * 0.0625f);
          }
        }
    }
  }
  __syncthreads();   // bar3: pol complete

  // ===== decode + store =====
  if (isbf) {
    u16* ob = (u16*)out + (size_t)b * 2187u;
    for (int p2 = tid; p2 < 2187; p2 += 256) ob[p2] = f2b(decf(pol[p2]));
  } else {
    float* ob = (float*)out + (size_t)b * 2187u;
    for (int p2 = tid; p2 < 2187; p2 += 256) ob[p2] = decf(pol[p2]);
  }
}

// ---------------- launcher ----------------
extern "C" void kernel_launch(void* const* d_in, const int* in_sizes, int n_in,
                              void* d_out, int out_size, void* d_ws, size_t ws_size,
                              hipStream_t stream) {
  const void* x        = d_in[0];
  const void* W_embed  = d_in[1];
  const void* b_embed  = d_in[2];
  const void* Wq       = d_in[3];
  const void* bq       = d_in[4];
  const void* Wk       = d_in[5];
  const void* bk_      = d_in[6];
  const void* dq       = d_in[7];
  const int* valid_idx         = (const int*)d_in[8];
  const int* policy_idx        = (const int*)d_in[9];
  const int* promo_idx         = (const int*)d_in[10];
  const int* promo_policy_idx  = (const int*)d_in[11];
  const int n_valid = in_sizes[8];
  const int n_promo = in_sizes[10];
  const int B = in_sizes[0] / 20736;   // 81*256

  // ws layout
  char* ws = (char*)d_ws;
  u8t* Wt8     = (u8t*)(ws);               // 65536
  u8t* Wqk8    = (u8t*)(ws + 65536);       // 65536
  u8t* dqkp8   = (u8t*)(ws + 131072);      // 1792 (+pad)
  u8t* uvw_tl  = (u8t*)(ws + 133120);      // 4096
  float* dqc   = (float*)(ws + 137216);    // 32
  int* dflag   = (int*)(ws + 137248);      // 32
  u32* invP    = (u32*)(ws + 137280);      // 26244
  if (ws_size < 164000) return;

  detect_dtype_kernel<<<dim3(1), dim3(256), 0, stream>>>(x, dflag);
  prep_all<<<dim3(523), dim3(256), 0, stream>>>(
      W_embed, Wq, Wk, bq, bk_, dq,
      valid_idx, policy_idx, promo_idx, promo_policy_idx, n_valid, n_promo,
      Wt8, Wqk8, dqkp8, uvw_tl, dqc, invP, dflag);

  (void)hipFuncSetAttribute((const void*)dirpolicy_fp8,
                            hipFuncAttributeMaxDynamicSharedMemorySize, LDS_TOTAL);
  if (B > 0)
    dirpolicy_fp8<<<dim3(B), dim3(256), LDS_TOTAL, stream>>>(
        x, b_embed, Wt8, Wqk8, dqkp8, uvw_tl, dqc, invP, d_out, dflag);
}

// Round 11
// 311.551 us; speedup vs baseline: 1.7689x; 1.7689x over previous
//
#include <hip/hip_runtime.h>

typedef unsigned short u16;
typedef unsigned int u32;
typedef unsigned char u8t;
using bfrag = __attribute__((ext_vector_type(8))) short;   // 8 x bf16 (raw bits)
using facc  = __attribute__((ext_vector_type(4))) float;   // MFMA accumulator

// ---------------- numeric helpers ----------------
__device__ __forceinline__ u16 f2b(float f) {              // f32 -> bf16 (RNE)
  u32 u = __float_as_uint(f);
  return (u16)((u + 0x7FFFu + ((u >> 16) & 1u)) >> 16);
}
__device__ __forceinline__ float b2f(u16 h) { return __uint_as_float(((u32)h) << 16); }
__device__ __forceinline__ u32 encf(float f) {             // order-preserving f32->u32
  u32 u = __float_as_uint(f);
  return (u & 0x80000000u) ? ~u : (u | 0x80000000u);
}
__device__ __forceinline__ float decf(u32 e) {
  return __uint_as_float((e & 0x80000000u) ? (e & 0x7FFFFFFFu) : ~e);
}
// branchless mish: v*tanh(softplus(v)) = v - 2v/(e^v(e^v+2)+2)
__device__ __forceinline__ float mish_f(float v) {
  float ev = __expf(v);
  float d = __builtin_fmaf(ev, ev + 2.f, 2.f);
  return __builtin_fmaf(-2.f * v, __builtin_amdgcn_rcpf(d), v);
}
__device__ __forceinline__ float ldf(const void* p, int i, int bf) {
  return bf ? b2f(((const u16*)p)[i]) : ((const float*)p)[i];
}
__device__ __forceinline__ u8t f2fp8(float f) {            // f32 -> fp8 e4m3 (OCP)
  return (u8t)(__builtin_amdgcn_cvt_pk_fp8_f32(f, f, 0, 0) & 0xFF);
}
// fp8 LDS tile: row stride 256B, XOR swizzle bits 4..6
__device__ __forceinline__ char* tp8(char* base, int row, int colb) {
  return base + ((row << 8) + (colb ^ ((row & 7) << 4)));
}

// ---------------- dtype detector ----------------
__global__ void detect_dtype_kernel(const void* __restrict__ x, int* __restrict__ flag) {
  __shared__ int cnt;
  const int tid = threadIdx.x;
  if (tid == 0) cnt = 0;
  __syncthreads();
  const u16* p = (const u16*)x;
  u16 h = p[tid * 96 + 4];
  int e = (int)((h >> 7) & 0xFF);
  if (e >= 116 && e <= 134) atomicAdd(&cnt, 1);
  __syncthreads();
  if (tid == 0) *flag = (cnt >= 128) ? 1 : 0;
}

// ---------------- consolidated prep (523 blocks, 256 thr) ----------------
// bid<256: W_embed col-tiles -> Wt8 ; bid<512: Wqk -> Wqk8 ; bid<519: dqkp8 ;
// bid==519: dqc ; bid==521: invP ; bid==522: uvw_tl tiles (parallel dot + LDS relayout)
__global__ void prep_all(const void* __restrict__ W_embed,
                         const void* __restrict__ Wq, const void* __restrict__ Wk,
                         const void* __restrict__ bq, const void* __restrict__ bk,
                         const void* __restrict__ dq,
                         const int* __restrict__ vi, const int* __restrict__ pi,
                         const int* __restrict__ qi, const int* __restrict__ qpi,
                         int nv, int np,
                         u8t* __restrict__ Wt8, u8t* __restrict__ Wqk8,
                         u8t* __restrict__ dqkp8, u8t* __restrict__ uvw_tl,
                         float* __restrict__ dqc,
                         u32* __restrict__ invP, const int* __restrict__ dflag) {
  __shared__ float wkrow[256];
  __shared__ u16 wqt[64][260];
  __shared__ u8t u8l[256], w8l[256];
  const int bid = blockIdx.x;
  const int bf = *dflag;
  const int t = threadIdx.x;

  if (bid < 256) {                 // ---- Wt8 tiles ----
    const int k = bid, n = t;
    u8t v = f2fp8(ldf(W_embed, (k << 8) + n, bf));
    int nt = n >> 4, lr = n & 15, kt = k >> 5, lg = (k >> 3) & 3, e = k & 7;
    Wt8[(((nt << 3) + kt) << 9) + (((lg << 4) + lr) << 3) + e] = v;
  } else if (bid < 512) {          // ---- Wqk8 tiles ----
    const int n = bid - 256, k = t;
    wkrow[k] = ldf(Wk, (n << 8) + k, bf);
    float s = 0.f;
    for (int d0 = 0; d0 < 256; d0 += 64) {
      __syncthreads();
      for (int it = 0; it < 64; ++it) {
        int kk = (it << 2) + (t >> 6);
        int dd = t & 63;
        wqt[dd][kk] = f2b(ldf(Wq, (kk << 8) + d0 + dd, bf));
      }
      __syncthreads();
      #pragma unroll 8
      for (int dd = 0; dd < 64; ++dd) s += b2f(wqt[dd][k]) * wkrow[d0 + dd];
    }
    int nt = n >> 4, lr = n & 15, kt = k >> 5, lg = (k >> 3) & 3, e = k & 7;
    Wqk8[(((nt << 3) + kt) << 9) + (((lg << 4) + lr) << 3) + e] = f2fp8(s);
  } else if (bid < 519) {          // ---- dqkp rows ----
    const int blk = bid - 512, d = t;
    float s = 0.f;
    for (int nn = 0; nn < 256; ++nn)
      s += ldf(Wk, (d << 8) + nn, bf) * ldf(dq, (blk << 8) + nn, bf);
    dqkp8[(blk << 8) + d] = f2fp8(s);
  } else if (bid == 519) {         // ---- dqc ----
    if (t < 7) {
      float s = 0.f;
      for (int nn = 0; nn < 256; ++nn) s += ldf(dq, (t << 8) + nn, bf) * ldf(bk, nn, bf);
      dqc[t] = s;
    } else if (t == 7) {
      float s = 0.f;
      for (int nn = 0; nn < 256; ++nn) s += ldf(bq, nn, bf) * ldf(bk, nn, bf);
      dqc[7] = s;
    }
  } else if (bid == 521) {         // ---- invP ----
    for (int i = t; i < 6561; i += 256) invP[i] = 0u;
    __syncthreads();
    for (int i = t; i < nv; i += 256) atomicOr(&invP[vi[i]], (u32)(pi[i] + 1));
    for (int i = t; i < np; i += 256) atomicOr(&invP[qi[i]], ((u32)(qpi[i] + 1)) << 16);
  } else if (bid == 522) {         // ---- uvw tiles: parallel dots, then relayout ----
    // phase a: thread t computes u[t]=Wq[t,:].bk, w[t]=Wk[t,:].bq (all lanes active)
    {
      float su = 0.f, sw = 0.f;
      for (int nn = 0; nn < 256; ++nn) {
        su += ldf(Wq, (t << 8) + nn, bf) * ldf(bk, nn, bf);
        sw += ldf(Wk, (t << 8) + nn, bf) * ldf(bq, nn, bf);
      }
      u8l[t] = f2fp8(su);
      w8l[t] = f2fp8(sw);
    }
    __syncthreads();
    // phase b: A-fragment tiles. s = kt*64 + lane; lane lr2 covers A-row (0=u,1=w),
    // element e covers k = kt*32 + lg2*8 + e.
    for (int s = t; s < 512; s += 256) {
      int kt = s >> 6, ln = s & 63, lr2 = ln & 15, lg2 = ln >> 4;
      #pragma unroll
      for (int e = 0; e < 8; ++e) {
        int k = kt * 32 + lg2 * 8 + e;
        u8t v = (lr2 == 0) ? u8l[k] : (lr2 == 1) ? w8l[k] : (u8t)0;
        uvw_tl[(s << 3) + e] = v;
      }
    }
  }
}

// ---------------- fused kernel: 256 thr, 1 element/block, 3 blocks/CU ----------------
// LDS (52864 B, 3x = 158592 <= 160K):
//   bufA @0      [88][256] fp8 swz  (x rows 0..80 -> T; rows 81..87 = dqkp)
//   bufP @22528  [81][256] fp8 swz  (pe)  [frag reads of rows 81..95 spill into pol
//                                          region -> garbage feeding DISCARDED rows/cols]
//   pol  @43264  [2187] u32
//   alpha@52012 [96] f32 ; beta@52396 [96] f32 ; dqcS@52780 [8] f32
#define LDS_TOTAL 52864

// (256,3): 3 waves/EU. Allocator splits unified file evenly (84 arch + 84 acc of 168)
// when AGPRs are in use -> keep AGPR peak <= 24 (one acc set at a time, unroll 1 on
// pass loops) and arch bursts small (staging unroll 2) so neither side exceeds 84.
__global__ __launch_bounds__(256, 3)
void dirpolicy_fp8(const void* __restrict__ x,
                   const void* __restrict__ b_embed,
                   const u8t* __restrict__ Wt8,
                   const u8t* __restrict__ Wqk8,
                   const u8t* __restrict__ dqkp8,
                   const u8t* __restrict__ uvw_tl,
                   const float* __restrict__ dqc,
                   const u32* __restrict__ invP,
                   void* __restrict__ out,
                   const int* __restrict__ dflag) {
  extern __shared__ char smem[];
  char* bufA = smem;
  char* bufP = smem + 22528;
  u32* pol = (u32*)(smem + 43264);
  float* alpha = (float*)(smem + 52012);
  float* beta  = (float*)(smem + 52396);
  float* dqcS  = (float*)(smem + 52780);

  const int tid = threadIdx.x;
  const int lane = tid & 63;
  const int w = tid >> 6;          // wave 0..3
  const int lr = lane & 15;
  const int lg = lane >> 4;
  const int isbf = *dflag;
  const int b = blockIdx.x;
  const u32 ENEG = encf(-1e10f);

  // ---- prologue: consts + pol init ----
  for (int i = tid; i < 1792; i += 256) {      // bufA rows 81..87 = dqkp
    int q = i >> 8, d = i & 255;
    *tp8(bufA, 81 + q, d) = dqkp8[i];
  }
  for (int i = tid; i < 2187; i += 256) pol[i] = ENEG;
  if (tid < 8) dqcS[tid] = dqc[tid];

  // ---- stage x -> bufA rows 0..80 (fp8); unroll 2 keeps load burst small ----
  if (isbf) {
    const u16* xb = (const u16*)x + (size_t)b * 20736u;
    #pragma unroll 2
    for (int c = 0; c < 11; ++c) {
      int idx = tid + (c << 8);
      if (idx < 2592) {
        bfrag v = *(const bfrag*)(xb + (idx << 3));
        u32 lo = __builtin_amdgcn_cvt_pk_fp8_f32(b2f((u16)v[0]), b2f((u16)v[1]), 0, 0);
        lo = __builtin_amdgcn_cvt_pk_fp8_f32(b2f((u16)v[2]), b2f((u16)v[3]), lo, 1);
        u32 hi = __builtin_amdgcn_cvt_pk_fp8_f32(b2f((u16)v[4]), b2f((u16)v[5]), 0, 0);
        hi = __builtin_amdgcn_cvt_pk_fp8_f32(b2f((u16)v[6]), b2f((u16)v[7]), hi, 1);
        uint2 pk; pk.x = lo; pk.y = hi;
        *(uint2*)tp8(bufA, idx >> 5, (idx & 31) << 3) = pk;
      }
    }
  } else {
    const float4* xs = (const float4*)((const float*)x + (size_t)b * 20736u);
    #pragma unroll 2
    for (int c = 0; c < 11; ++c) {
      int idx = tid + (c << 8);
      if (idx < 2592) {
        float4 p0 = xs[idx * 2], p1 = xs[idx * 2 + 1];
        u32 lo = __builtin_amdgcn_cvt_pk_fp8_f32(p0.x, p0.y, 0, 0);
        lo = __builtin_amdgcn_cvt_pk_fp8_f32(p0.z, p0.w, lo, 1);
        u32 hi = __builtin_amdgcn_cvt_pk_fp8_f32(p1.x, p1.y, 0, 0);
        hi = __builtin_amdgcn_cvt_pk_fp8_f32(p1.z, p1.w, hi, 1);
        uint2 pk; pk.x = lo; pk.y = hi;
        *(uint2*)tp8(bufA, idx >> 5, (idx & 31) << 3) = pk;
      }
    }
  }
  __syncthreads();   // bar0: x + consts + pol staged

  // ===== phase 1: pe = mish(x @ We + b) -> bufP; 4 sequential acc[3][2] passes =====
  #pragma unroll 1
  for (int rh = 0; rh < 2; ++rh) {
    #pragma unroll 1
    for (int jh = 0; jh < 2; ++jh) {
      facc acc[3][2];
      facc z4 = {0.f, 0.f, 0.f, 0.f};
      #pragma unroll
      for (int i = 0; i < 3; ++i)
        #pragma unroll
        for (int jj = 0; jj < 2; ++jj) acc[i][jj] = z4;
      #pragma unroll
      for (int kt = 0; kt < 8; ++kt) {
        long bb[2], a[3];
        #pragma unroll
        for (int jj = 0; jj < 2; ++jj)
          bb[jj] = *(const long*)(Wt8 + (((((w << 2) + (jh << 1) + jj) << 3) + kt) << 9) + (lane << 3));
        #pragma unroll
        for (int i = 0; i < 3; ++i)
          a[i] = *(const long*)tp8(bufA, rh * 48 + i * 16 + lr, (kt << 5) + (lg << 3));
        #pragma unroll
        for (int i = 0; i < 3; ++i)
          #pragma unroll
          for (int jj = 0; jj < 2; ++jj)
            acc[i][jj] = __builtin_amdgcn_mfma_f32_16x16x32_fp8_fp8(a[i], bb[jj], acc[i][jj], 0, 0, 0);
      }
      #pragma unroll
      for (int jj = 0; jj < 2; ++jj) {
        const int col = (w << 6) + ((jh << 1) + jj) * 16 + lr;
        const float bias = ldf(b_embed, col, isbf);
        #pragma unroll
        for (int i = 0; i < 3; ++i)
          #pragma unroll
          for (int r = 0; r < 4; ++r) {
            const int row = rh * 48 + i * 16 + (lg << 2) + r;
            if (row < 81)
              *tp8(bufP, row, col) = f2fp8(mish_f(acc[i][jj][r] + bias));
          }
      }
    }
  }
  __syncthreads();   // bar1: pe complete; bufA rows<81 free

  // ===== mini-GEMM: alpha/beta = [u;w] @ pe^T (waves 0..2, 8 AGPR) =====
  if (w < 3) {
    facc ae0, ae1;
    {
      facc z4 = {0.f, 0.f, 0.f, 0.f};
      ae0 = z4; ae1 = z4;
    }
    #pragma unroll
    for (int kt = 0; kt < 8; ++kt) {
      long av = *(const long*)(uvw_tl + (kt << 9) + (lane << 3));
      long b0 = *(const long*)tp8(bufP, (w << 5) + lr, (kt << 5) + (lg << 3));
      long b1 = *(const long*)tp8(bufP, (w << 5) + 16 + lr, (kt << 5) + (lg << 3));
      ae0 = __builtin_amdgcn_mfma_f32_16x16x32_fp8_fp8(av, b0, ae0, 0, 0, 0);
      ae1 = __builtin_amdgcn_mfma_f32_16x16x32_fp8_fp8(av, b1, ae1, 0, 0, 0);
    }
    if (lg == 0) {                    // C rows 0 (u-dot) and 1 (w-dot) live in lg==0, r=0/1
      const float c7 = dqcS[7];
      const int col0 = (w << 5) + lr, col1 = col0 + 16;
      if (col0 < 81) { alpha[col0] = (ae0[0] + c7) * 0.0625f; beta[col0] = ae0[1] * 0.0625f; }
      if (col1 < 81) { alpha[col1] = (ae1[0] + c7) * 0.0625f; beta[col1] = ae1[1] * 0.0625f; }
    }
  }

  // ===== phase 3: T = pe @ Wqk -> bufA rows 0..80; 4 sequential passes =====
  #pragma unroll 1
  for (int rh = 0; rh < 2; ++rh) {
    #pragma unroll 1
    for (int jh = 0; jh < 2; ++jh) {
      facc acc2[3][2];
      facc z4 = {0.f, 0.f, 0.f, 0.f};
      #pragma unroll
      for (int i = 0; i < 3; ++i)
        #pragma unroll
        for (int jj = 0; jj < 2; ++jj) acc2[i][jj] = z4;
      #pragma unroll
      for (int kt = 0; kt < 8; ++kt) {
        long bb[2], a[3];
        #pragma unroll
        for (int jj = 0; jj < 2; ++jj)
          bb[jj] = *(const long*)(Wqk8 + (((((w << 2) + (jh << 1) + jj) << 3) + kt) << 9) + (lane << 3));
        #pragma unroll
        for (int i = 0; i < 3; ++i)
          a[i] = *(const long*)tp8(bufP, rh * 48 + i * 16 + lr, (kt << 5) + (lg << 3));
        #pragma unroll
        for (int i = 0; i < 3; ++i)
          #pragma unroll
          for (int jj = 0; jj < 2; ++jj)
            acc2[i][jj] = __builtin_amdgcn_mfma_f32_16x16x32_fp8_fp8(a[i], bb[jj], acc2[i][jj], 0, 0, 0);
      }
      #pragma unroll
      for (int jj = 0; jj < 2; ++jj) {
        const int col = (w << 6) + ((jh << 1) + jj) * 16 + lr;
        #pragma unroll
        for (int i = 0; i < 3; ++i)
          #pragma unroll
          for (int r = 0; r < 4; ++r) {
            const int row = rh * 48 + i * 16 + (lg << 2) + r;
            if (row < 81) *tp8(bufA, row, col) = f2fp8(acc2[i][jj][r]);
          }
      }
    }
  }
  __syncthreads();   // bar2: T + alpha/beta visible

  // ===== phase 4: board = [T;dqkp] @ pe^T, 2x2 wave grid, two column passes;
  //       scatter each pass straight from its accumulators (<=24 AGPR live) =====
  const int wr4 = w >> 1;          // rows wr4*48..+47
  const int wc4 = w & 1;           // cols wc4*48..+47
  #pragma unroll 1
  for (int pass = 0; pass < 2; ++pass) {
    const int nj = pass ? 1 : 2;
    const int jb = pass ? 2 : 0;
    facc bd[3][2];
    {
      facc z4 = {0.f, 0.f, 0.f, 0.f};
      #pragma unroll
      for (int i = 0; i < 3; ++i)
        #pragma unroll
        for (int jj = 0; jj < 2; ++jj) bd[i][jj] = z4;
    }
    #pragma unroll
    for (int kt = 0; kt < 8; ++kt) {
      long a[3], bb[2];
      #pragma unroll
      for (int i = 0; i < 3; ++i)
        a[i] = *(const long*)tp8(bufA, wr4 * 48 + i * 16 + lr, (kt << 5) + (lg << 3));
      #pragma unroll
      for (int jj = 0; jj < 2; ++jj)
        bb[jj] = (jj < nj)
          ? *(const long*)tp8(bufP, wc4 * 48 + (jb + jj) * 16 + lr, (kt << 5) + (lg << 3))
          : 0L;
      #pragma unroll
      for (int i = 0; i < 3; ++i)
        #pragma unroll
        for (int jj = 0; jj < 2; ++jj)
          if (jj < nj)
            bd[i][jj] = __builtin_amdgcn_mfma_f32_16x16x32_fp8_fp8(a[i], bb[jj], bd[i][jj], 0, 0, 0);
    }
    // scatter this pass (alpha/beta ready since bar2; pol inited at prologue)
    #pragma unroll
    for (int jj = 0; jj < 2; ++jj) {
      if (jj >= nj) continue;
      const int colb = wc4 * 48 + (jb + jj) * 16 + lr;
      const float betv = (colb < 81) ? beta[colb] : 0.f;
      #pragma unroll
      for (int i = 0; i < 3; ++i)
        #pragma unroll
        for (int r = 0; r < 4; ++r) {
          const int rowb = wr4 * 48 + i * 16 + (lg << 2) + r;
          if (rowb < 81) {
            if (colb < 81) {
              const u32 ev = encf(bd[i][jj][r] * 0.0625f + alpha[rowb] + betv);
              const u32 pv = invP[rowb * 81 + colb];
              if (pv & 0xFFFFu) atomicMax(&pol[(pv & 0xFFFFu) - 1], ev);
              if (pv >> 16)     atomicMax(&pol[(pv >> 16) - 1], ev);
            }
          } else if (rowb < 88 && colb < 81) {
            pol[1620 + (rowb - 81) * 81 + colb] =
                encf((bd[i][jj][r] + dqcS[rowb - 81]) * 0.0625f);
          }
        }
    }
  }
  __syncthreads();   // bar3: pol complete

  // ===== decode + store =====
  if (isbf) {
    u16* ob = (u16*)out + (size_t)b * 2187u;
    for (int p2 = tid; p2 < 2187; p2 += 256) ob[p2] = f2b(decf(pol[p2]));
  } else {
    float* ob = (float*)out + (size_t)b * 2187u;
    for (int p2 = tid; p2 < 2187; p2 += 256) ob[p2] = decf(pol[p2]);
  }
}

// ---------------- launcher ----------------
extern "C" void kernel_launch(void* const* d_in, const int* in_sizes, int n_in,
                              void* d_out, int out_size, void* d_ws, size_t ws_size,
                              hipStream_t stream) {
  const void* x        = d_in[0];
  const void* W_embed  = d_in[1];
  const void* b_embed  = d_in[2];
  const void* Wq       = d_in[3];
  const void* bq       = d_in[4];
  const void* Wk       = d_in[5];
  const void* bk_      = d_in[6];
  const void* dq       = d_in[7];
  const int* valid_idx         = (const int*)d_in[8];
  const int* policy_idx        = (const int*)d_in[9];
  const int* promo_idx         = (const int*)d_in[10];
  const int* promo_policy_idx  = (const int*)d_in[11];
  const int n_valid = in_sizes[8];
  const int n_promo = in_sizes[10];
  const int B = in_sizes[0] / 20736;   // 81*256

  // ws layout
  char* ws = (char*)d_ws;
  u8t* Wt8     = (u8t*)(ws);               // 65536
  u8t* Wqk8    = (u8t*)(ws + 65536);       // 65536
  u8t* dqkp8   = (u8t*)(ws + 131072);      // 1792 (+pad)
  u8t* uvw_tl  = (u8t*)(ws + 133120);      // 4096
  float* dqc   = (float*)(ws + 137216);    // 32
  int* dflag   = (int*)(ws + 137248);      // 32
  u32* invP    = (u32*)(ws + 137280);      // 26244
  if (ws_size < 164000) return;

  detect_dtype_kernel<<<dim3(1), dim3(256), 0, stream>>>(x, dflag);
  prep_all<<<dim3(523), dim3(256), 0, stream>>>(
      W_embed, Wq, Wk, bq, bk_, dq,
      valid_idx, policy_idx, promo_idx, promo_policy_idx, n_valid, n_promo,
      Wt8, Wqk8, dqkp8, uvw_tl, dqc, invP, dflag);

  (void)hipFuncSetAttribute((const void*)dirpolicy_fp8,
                            hipFuncAttributeMaxDynamicSharedMemorySize, LDS_TOTAL);
  if (B > 0)
    dirpolicy_fp8<<<dim3(B), dim3(256), LDS_TOTAL, stream>>>(
        x, b_embed, Wt8, Wqk8, dqkp8, uvw_tl, dqc, invP, d_out, dflag);
}

// Round 12
// 284.611 us; speedup vs baseline: 1.9364x; 1.0947x over previous
//
#include <hip/hip_runtime.h>

typedef unsigned short u16;
typedef unsigned int u32;
typedef unsigned char u8t;
using bfrag = __attribute__((ext_vector_type(8))) short;   // 8 x bf16 (raw bits)
using facc  = __attribute__((ext_vector_type(4))) float;   // MFMA accumulator

// ---------------- numeric helpers ----------------
__device__ __forceinline__ u16 f2b(float f) {              // f32 -> bf16 (RNE)
  u32 u = __float_as_uint(f);
  return (u16)((u + 0x7FFFu + ((u >> 16) & 1u)) >> 16);
}
__device__ __forceinline__ float b2f(u16 h) { return __uint_as_float(((u32)h) << 16); }
__device__ __forceinline__ u32 encf(float f) {             // order-preserving f32->u32
  u32 u = __float_as_uint(f);
  return (u & 0x80000000u) ? ~u : (u | 0x80000000u);
}
__device__ __forceinline__ float decf(u32 e) {
  return __uint_as_float((e & 0x80000000u) ? (e & 0x7FFFFFFFu) : ~e);
}
// branchless mish: v*tanh(softplus(v)) = v - 2v/(e^v(e^v+2)+2)
__device__ __forceinline__ float mish_f(float v) {
  float ev = __expf(v);
  float d = __builtin_fmaf(ev, ev + 2.f, 2.f);
  return __builtin_fmaf(-2.f * v, __builtin_amdgcn_rcpf(d), v);
}
__device__ __forceinline__ float ldf(const void* p, int i, int bf) {
  return bf ? b2f(((const u16*)p)[i]) : ((const float*)p)[i];
}
__device__ __forceinline__ u8t f2fp8(float f) {            // f32 -> fp8 e4m3 (OCP)
  return (u8t)(__builtin_amdgcn_cvt_pk_fp8_f32(f, f, 0, 0) & 0xFF);
}
// pack 4 f32 -> 4 fp8 bytes (2 cvt_pk instructions)
__device__ __forceinline__ u32 pk4fp8(float a, float b, float c, float d) {
  u32 v = __builtin_amdgcn_cvt_pk_fp8_f32(a, b, 0, 0);
  return __builtin_amdgcn_cvt_pk_fp8_f32(c, d, v, 1);
}
// fp8 LDS tile: row stride 256B, XOR swizzle bits 4..6
__device__ __forceinline__ char* tp8(char* base, int row, int colb) {
  return base + ((row << 8) + (colb ^ ((row & 7) << 4)));
}

// ---------------- dtype detector ----------------
__global__ void detect_dtype_kernel(const void* __restrict__ x, int* __restrict__ flag) {
  __shared__ int cnt;
  const int tid = threadIdx.x;
  if (tid == 0) cnt = 0;
  __syncthreads();
  const u16* p = (const u16*)x;
  u16 h = p[tid * 96 + 4];
  int e = (int)((h >> 7) & 0xFF);
  if (e >= 116 && e <= 134) atomicAdd(&cnt, 1);
  __syncthreads();
  if (tid == 0) *flag = (cnt >= 128) ? 1 : 0;
}

// ---------------- consolidated prep (523 blocks, 256 thr) ----------------
// bid<256: W_embed col-tiles -> Wt8 ; bid<512: Wqk -> Wqk8 ; bid<519: dqkp8 ;
// bid==519: dqc ; bid==521: invP ; bid==522: uvw_tl tiles
__global__ void prep_all(const void* __restrict__ W_embed,
                         const void* __restrict__ Wq, const void* __restrict__ Wk,
                         const void* __restrict__ bq, const void* __restrict__ bk,
                         const void* __restrict__ dq,
                         const int* __restrict__ vi, const int* __restrict__ pi,
                         const int* __restrict__ qi, const int* __restrict__ qpi,
                         int nv, int np,
                         u8t* __restrict__ Wt8, u8t* __restrict__ Wqk8,
                         u8t* __restrict__ dqkp8, u8t* __restrict__ uvw_tl,
                         float* __restrict__ dqc,
                         u32* __restrict__ invP, const int* __restrict__ dflag) {
  __shared__ float wkrow[256];
  __shared__ u16 wqt[64][260];
  __shared__ u8t u8l[256], w8l[256];
  const int bid = blockIdx.x;
  const int bf = *dflag;
  const int t = threadIdx.x;

  if (bid < 256) {                 // ---- Wt8 tiles ----
    const int k = bid, n = t;
    u8t v = f2fp8(ldf(W_embed, (k << 8) + n, bf));
    int nt = n >> 4, lr = n & 15, kt = k >> 5, lg = (k >> 3) & 3, e = k & 7;
    Wt8[(((nt << 3) + kt) << 9) + (((lg << 4) + lr) << 3) + e] = v;
  } else if (bid < 512) {          // ---- Wqk8 tiles (vectorized staging) ----
    const int n = bid - 256, k = t;
    wkrow[k] = ldf(Wk, (n << 8) + k, bf);
    float s = 0.f;
    for (int d0 = 0; d0 < 256; d0 += 64) {
      __syncthreads();
      if (bf) {
        for (int sI = t; sI < 2048; sI += 256) {      // 8 x (16B load + 8 LDS writes)
          int kk = sI >> 3, dg = (sI & 7) << 3;
          bfrag v = *(const bfrag*)((const u16*)Wq + (kk << 8) + d0 + dg);
          #pragma unroll
          for (int e = 0; e < 8; ++e) wqt[dg + e][kk] = (u16)v[e];
        }
      } else {
        for (int sI = t; sI < 2048; sI += 256) {
          int kk = sI >> 3, dg = (sI & 7) << 3;
          const float* wp = (const float*)Wq + (kk << 8) + d0 + dg;
          float4 p0 = *(const float4*)wp, p1 = *(const float4*)(wp + 4);
          wqt[dg + 0][kk] = f2b(p0.x); wqt[dg + 1][kk] = f2b(p0.y);
          wqt[dg + 2][kk] = f2b(p0.z); wqt[dg + 3][kk] = f2b(p0.w);
          wqt[dg + 4][kk] = f2b(p1.x); wqt[dg + 5][kk] = f2b(p1.y);
          wqt[dg + 6][kk] = f2b(p1.z); wqt[dg + 7][kk] = f2b(p1.w);
        }
      }
      __syncthreads();
      #pragma unroll 8
      for (int dd = 0; dd < 64; ++dd) s += b2f(wqt[dd][k]) * wkrow[d0 + dd];
    }
    int nt = n >> 4, lr = n & 15, kt = k >> 5, lg = (k >> 3) & 3, e = k & 7;
    Wqk8[(((nt << 3) + kt) << 9) + (((lg << 4) + lr) << 3) + e] = f2fp8(s);
  } else if (bid < 519) {          // ---- dqkp rows ----
    const int blk = bid - 512, d = t;
    float s = 0.f;
    for (int nn = 0; nn < 256; ++nn)
      s += ldf(Wk, (d << 8) + nn, bf) * ldf(dq, (blk << 8) + nn, bf);
    dqkp8[(blk << 8) + d] = f2fp8(s);
  } else if (bid == 519) {         // ---- dqc ----
    if (t < 7) {
      float s = 0.f;
      for (int nn = 0; nn < 256; ++nn) s += ldf(dq, (t << 8) + nn, bf) * ldf(bk, nn, bf);
      dqc[t] = s;
    } else if (t == 7) {
      float s = 0.f;
      for (int nn = 0; nn < 256; ++nn) s += ldf(bq, nn, bf) * ldf(bk, nn, bf);
      dqc[7] = s;
    }
  } else if (bid == 521) {         // ---- invP ----
    for (int i = t; i < 6561; i += 256) invP[i] = 0u;
    __syncthreads();
    for (int i = t; i < nv; i += 256) atomicOr(&invP[vi[i]], (u32)(pi[i] + 1));
    for (int i = t; i < np; i += 256) atomicOr(&invP[qi[i]], ((u32)(qpi[i] + 1)) << 16);
  } else if (bid == 522) {         // ---- uvw tiles: parallel dots, then relayout ----
    {
      float su = 0.f, sw = 0.f;
      for (int nn = 0; nn < 256; ++nn) {
        su += ldf(Wq, (t << 8) + nn, bf) * ldf(bk, nn, bf);
        sw += ldf(Wk, (t << 8) + nn, bf) * ldf(bq, nn, bf);
      }
      u8l[t] = f2fp8(su);
      w8l[t] = f2fp8(sw);
    }
    __syncthreads();
    for (int s = t; s < 512; s += 256) {
      int kt = s >> 6, ln = s & 63, lr2 = ln & 15, lg2 = ln >> 4;
      #pragma unroll
      for (int e = 0; e < 8; ++e) {
        int k = kt * 32 + lg2 * 8 + e;
        u8t v = (lr2 == 0) ? u8l[k] : (lr2 == 1) ? w8l[k] : (u8t)0;
        uvw_tl[(s << 3) + e] = v;
      }
    }
  }
}

// ---------------- fused kernel: 256 thr, 1 element/block, 3 blocks/CU ----------------
// LDS (52864 B, 3x = 158592 <= 160K):
//   bufA @0      [88][256] fp8 swz  (x rows 0..80 -> T; rows 81..87 = dqkp)
//   bufP @22528  [81][256] fp8 swz  (pe)  [frag reads of rows 81..95 spill into pol
//                                          region -> garbage feeding DISCARDED rows/cols]
//   pol  @43264  [2187] u32
//   alpha@52012 [96] f32 ; beta@52396 [96] f32 ; dqcS@52780 [8] f32
#define LDS_TOTAL 52864

// (256,3): 3 waves/EU, even 84/84 arch/acc split of the unified file; AGPR peak 24
// (one acc set, unroll 1 pass loops), arch ~76-90.
// Phases 1/3 use SWAPPED operands mfma(B,A): each lane's 4 acc values land on 4
// consecutive d-columns of ONE row -> epilogue = 2 cvt_pk + 1 ds_write_b32
// (was 4 cvt + 4 ds_write_b8). Write banks conflict-free under the same swizzle.
__global__ __launch_bounds__(256, 3)
void dirpolicy_fp8(const void* __restrict__ x,
                   const void* __restrict__ b_embed,
                   const u8t* __restrict__ Wt8,
                   const u8t* __restrict__ Wqk8,
                   const u8t* __restrict__ dqkp8,
                   const u8t* __restrict__ uvw_tl,
                   const float* __restrict__ dqc,
                   const u32* __restrict__ invP,
                   void* __restrict__ out,
                   const int* __restrict__ dflag) {
  extern __shared__ char smem[];
  char* bufA = smem;
  char* bufP = smem + 22528;
  u32* pol = (u32*)(smem + 43264);
  float* alpha = (float*)(smem + 52012);
  float* beta  = (float*)(smem + 52396);
  float* dqcS  = (float*)(smem + 52780);

  const int tid = threadIdx.x;
  const int lane = tid & 63;
  const int w = tid >> 6;          // wave 0..3
  const int lr = lane & 15;
  const int lg = lane >> 4;
  const int isbf = *dflag;
  const int b = blockIdx.x;
  const u32 ENEG = encf(-1e10f);

  // ---- prologue: consts + pol init ----
  for (int i = tid; i < 1792; i += 256) {      // bufA rows 81..87 = dqkp
    int q = i >> 8, d = i & 255;
    *tp8(bufA, 81 + q, d) = dqkp8[i];
  }
  for (int i = tid; i < 2187; i += 256) pol[i] = ENEG;
  if (tid < 8) dqcS[tid] = dqc[tid];

  // ---- stage x -> bufA rows 0..80 (fp8); unroll 2 keeps load burst small ----
  if (isbf) {
    const u16* xb = (const u16*)x + (size_t)b * 20736u;
    #pragma unroll 2
    for (int c = 0; c < 11; ++c) {
      int idx = tid + (c << 8);
      if (idx < 2592) {
        bfrag v = *(const bfrag*)(xb + (idx << 3));
        u32 lo = pk4fp8(b2f((u16)v[0]), b2f((u16)v[1]), b2f((u16)v[2]), b2f((u16)v[3]));
        u32 hi = pk4fp8(b2f((u16)v[4]), b2f((u16)v[5]), b2f((u16)v[6]), b2f((u16)v[7]));
        uint2 pk; pk.x = lo; pk.y = hi;
        *(uint2*)tp8(bufA, idx >> 5, (idx & 31) << 3) = pk;
      }
    }
  } else {
    const float4* xs = (const float4*)((const float*)x + (size_t)b * 20736u);
    #pragma unroll 2
    for (int c = 0; c < 11; ++c) {
      int idx = tid + (c << 8);
      if (idx < 2592) {
        float4 p0 = xs[idx * 2], p1 = xs[idx * 2 + 1];
        u32 lo = pk4fp8(p0.x, p0.y, p0.z, p0.w);
        u32 hi = pk4fp8(p1.x, p1.y, p1.z, p1.w);
        uint2 pk; pk.x = lo; pk.y = hi;
        *(uint2*)tp8(bufA, idx >> 5, (idx & 31) << 3) = pk;
      }
    }
  }
  __syncthreads();   // bar0: x + consts + pol staged

  // ===== phase 1: pe = mish(x @ We + b) -> bufP; swapped mfma, packed writes =====
  #pragma unroll 1
  for (int rh = 0; rh < 2; ++rh) {
    #pragma unroll 1
    for (int jh = 0; jh < 2; ++jh) {
      facc acc[3][2];
      facc z4 = {0.f, 0.f, 0.f, 0.f};
      #pragma unroll
      for (int i = 0; i < 3; ++i)
        #pragma unroll
        for (int jj = 0; jj < 2; ++jj) acc[i][jj] = z4;
      #pragma unroll
      for (int kt = 0; kt < 8; ++kt) {
        long bb[2], a[3];
        #pragma unroll
        for (int jj = 0; jj < 2; ++jj)
          bb[jj] = *(const long*)(Wt8 + (((((w << 2) + (jh << 1) + jj) << 3) + kt) << 9) + (lane << 3));
        #pragma unroll
        for (int i = 0; i < 3; ++i)
          a[i] = *(const long*)tp8(bufA, rh * 48 + i * 16 + lr, (kt << 5) + (lg << 3));
        #pragma unroll
        for (int i = 0; i < 3; ++i)
          #pragma unroll
          for (int jj = 0; jj < 2; ++jj)   // SWAPPED: C[m=wcol][n=xrow]
            acc[i][jj] = __builtin_amdgcn_mfma_f32_16x16x32_fp8_fp8(bb[jj], a[i], acc[i][jj], 0, 0, 0);
      }
      #pragma unroll
      for (int jj = 0; jj < 2; ++jj) {
        const int dbase = (w << 6) + ((jh << 1) + jj) * 16 + (lg << 2);
        const float b0 = ldf(b_embed, dbase + 0, isbf);
        const float b1 = ldf(b_embed, dbase + 1, isbf);
        const float b2 = ldf(b_embed, dbase + 2, isbf);
        const float b3 = ldf(b_embed, dbase + 3, isbf);
        #pragma unroll
        for (int i = 0; i < 3; ++i) {
          const int row = rh * 48 + i * 16 + lr;   // x-row
          if (row < 81) {
            u32 pk4 = pk4fp8(mish_f(acc[i][jj][0] + b0), mish_f(acc[i][jj][1] + b1),
                             mish_f(acc[i][jj][2] + b2), mish_f(acc[i][jj][3] + b3));
            *(u32*)tp8(bufP, row, dbase) = pk4;
          }
        }
      }
    }
  }
  __syncthreads();   // bar1: pe complete; bufA rows<81 free

  // ===== mini-GEMM: alpha/beta = [u;w] @ pe^T (waves 0..2, 8 AGPR) =====
  if (w < 3) {
    facc ae0, ae1;
    {
      facc z4 = {0.f, 0.f, 0.f, 0.f};
      ae0 = z4; ae1 = z4;
    }
    #pragma unroll
    for (int kt = 0; kt < 8; ++kt) {
      long av = *(const long*)(uvw_tl + (kt << 9) + (lane << 3));
      long b0 = *(const long*)tp8(bufP, (w << 5) + lr, (kt << 5) + (lg << 3));
      long b1 = *(const long*)tp8(bufP, (w << 5) + 16 + lr, (kt << 5) + (lg << 3));
      ae0 = __builtin_amdgcn_mfma_f32_16x16x32_fp8_fp8(av, b0, ae0, 0, 0, 0);
      ae1 = __builtin_amdgcn_mfma_f32_16x16x32_fp8_fp8(av, b1, ae1, 0, 0, 0);
    }
    if (lg == 0) {                    // C rows 0 (u-dot) and 1 (w-dot) live in lg==0, r=0/1
      const float c7 = dqcS[7];
      const int col0 = (w << 5) + lr, col1 = col0 + 16;
      if (col0 < 81) { alpha[col0] = (ae0[0] + c7) * 0.0625f; beta[col0] = ae0[1] * 0.0625f; }
      if (col1 < 81) { alpha[col1] = (ae1[0] + c7) * 0.0625f; beta[col1] = ae1[1] * 0.0625f; }
    }
  }

  // ===== phase 3: T = pe @ Wqk -> bufA rows 0..80; swapped mfma, packed writes =====
  #pragma unroll 1
  for (int rh = 0; rh < 2; ++rh) {
    #pragma unroll 1
    for (int jh = 0; jh < 2; ++jh) {
      facc acc2[3][2];
      facc z4 = {0.f, 0.f, 0.f, 0.f};
      #pragma unroll
      for (int i = 0; i < 3; ++i)
        #pragma unroll
        for (int jj = 0; jj < 2; ++jj) acc2[i][jj] = z4;
      #pragma unroll
      for (int kt = 0; kt < 8; ++kt) {
        long bb[2], a[3];
        #pragma unroll
        for (int jj = 0; jj < 2; ++jj)
          bb[jj] = *(const long*)(Wqk8 + (((((w << 2) + (jh << 1) + jj) << 3) + kt) << 9) + (lane << 3));
        #pragma unroll
        for (int i = 0; i < 3; ++i)
          a[i] = *(const long*)tp8(bufP, rh * 48 + i * 16 + lr, (kt << 5) + (lg << 3));
        #pragma unroll
        for (int i = 0; i < 3; ++i)
          #pragma unroll
          for (int jj = 0; jj < 2; ++jj)   // SWAPPED
            acc2[i][jj] = __builtin_amdgcn_mfma_f32_16x16x32_fp8_fp8(bb[jj], a[i], acc2[i][jj], 0, 0, 0);
      }
      #pragma unroll
      for (int jj = 0; jj < 2; ++jj) {
        const int dbase = (w << 6) + ((jh << 1) + jj) * 16 + (lg << 2);
        #pragma unroll
        for (int i = 0; i < 3; ++i) {
          const int row = rh * 48 + i * 16 + lr;   // pe-row
          if (row < 81) {
            u32 pk4 = pk4fp8(acc2[i][jj][0], acc2[i][jj][1], acc2[i][jj][2], acc2[i][jj][3]);
            *(u32*)tp8(bufA, row, dbase) = pk4;
          }
        }
      }
    }
  }
  __syncthreads();   // bar2: T + alpha/beta visible

  // ===== phase 4: board = [T;dqkp] @ pe^T, 2x2 wave grid, two column passes;
  //       scatter each pass straight from its accumulators (<=24 AGPR live) =====
  const int wr4 = w >> 1;          // rows wr4*48..+47
  const int wc4 = w & 1;           // cols wc4*48..+47
  #pragma unroll 1
  for (int pass = 0; pass < 2; ++pass) {
    const int nj = pass ? 1 : 2;
    const int jb = pass ? 2 : 0;
    facc bd[3][2];
    {
      facc z4 = {0.f, 0.f, 0.f, 0.f};
      #pragma unroll
      for (int i = 0; i < 3; ++i)
        #pragma unroll
        for (int jj = 0; jj < 2; ++jj) bd[i][jj] = z4;
    }
    #pragma unroll
    for (int kt = 0; kt < 8; ++kt) {
      long a[3], bb[2];
      #pragma unroll
      for (int i = 0; i < 3; ++i)
        a[i] = *(const long*)tp8(bufA, wr4 * 48 + i * 16 + lr, (kt << 5) + (lg << 3));
      #pragma unroll
      for (int jj = 0; jj < 2; ++jj)
        bb[jj] = (jj < nj)
          ? *(const long*)tp8(bufP, wc4 * 48 + (jb + jj) * 16 + lr, (kt << 5) + (lg << 3))
          : 0L;
      #pragma unroll
      for (int i = 0; i < 3; ++i)
        #pragma unroll
        for (int jj = 0; jj < 2; ++jj)
          if (jj < nj)
            bd[i][jj] = __builtin_amdgcn_mfma_f32_16x16x32_fp8_fp8(a[i], bb[jj], bd[i][jj], 0, 0, 0);
    }
    // scatter this pass (alpha/beta ready since bar2; pol inited at prologue)
    #pragma unroll
    for (int jj = 0; jj < 2; ++jj) {
      if (jj >= nj) continue;
      const int colb = wc4 * 48 + (jb + jj) * 16 + lr;
      const float betv = (colb < 81) ? beta[colb] : 0.f;
      #pragma unroll
      for (int i = 0; i < 3; ++i)
        #pragma unroll
        for (int r = 0; r < 4; ++r) {
          const int rowb = wr4 * 48 + i * 16 + (lg << 2) + r;
          if (rowb < 81) {
            if (colb < 81) {
              const u32 ev = encf(bd[i][jj][r] * 0.0625f + alpha[rowb] + betv);
              const u32 pv = invP[rowb * 81 + colb];
              if (pv & 0xFFFFu) atomicMax(&pol[(pv & 0xFFFFu) - 1], ev);
              if (pv >> 16)     atomicMax(&pol[(pv >> 16) - 1], ev);
            }
          } else if (rowb < 88 && colb < 81) {
            pol[1620 + (rowb - 81) * 81 + colb] =
                encf((bd[i][jj][r] + dqcS[rowb - 81]) * 0.0625f);
          }
        }
    }
  }
  __syncthreads();   // bar3: pol complete

  // ===== decode + store =====
  if (isbf) {
    u16* ob = (u16*)out + (size_t)b * 2187u;
    for (int p2 = tid; p2 < 2187; p2 += 256) ob[p2] = f2b(decf(pol[p2]));
  } else {
    float* ob = (float*)out + (size_t)b * 2187u;
    for (int p2 = tid; p2 < 2187; p2 += 256) ob[p2] = decf(pol[p2]);
  }
}

// ---------------- launcher ----------------
extern "C" void kernel_launch(void* const* d_in, const int* in_sizes, int n_in,
                              void* d_out, int out_size, void* d_ws, size_t ws_size,
                              hipStream_t stream) {
  const void* x        = d_in[0];
  const void* W_embed  = d_in[1];
  const void* b_embed  = d_in[2];
  const void* Wq       = d_in[3];
  const void* bq       = d_in[4];
  const void* Wk       = d_in[5];
  const void* bk_      = d_in[6];
  const void* dq       = d_in[7];
  const int* valid_idx         = (const int*)d_in[8];
  const int* policy_idx        = (const int*)d_in[9];
  const int* promo_idx         = (const int*)d_in[10];
  const int* promo_policy_idx  = (const int*)d_in[11];
  const int n_valid = in_sizes[8];
  const int n_promo = in_sizes[10];
  const int B = in_sizes[0] / 20736;   // 81*256

  // ws layout
  char* ws = (char*)d_ws;
  u8t* Wt8     = (u8t*)(ws);               // 65536
  u8t* Wqk8    = (u8t*)(ws + 65536);       // 65536
  u8t* dqkp8   = (u8t*)(ws + 131072);      // 1792 (+pad)
  u8t* uvw_tl  = (u8t*)(ws + 133120);      // 4096
  float* dqc   = (float*)(ws + 137216);    // 32
  int* dflag   = (int*)(ws + 137248);      // 32
  u32* invP    = (u32*)(ws + 137280);      // 26244
  if (ws_size < 164000) return;

  detect_dtype_kernel<<<dim3(1), dim3(256), 0, stream>>>(x, dflag);
  prep_all<<<dim3(523), dim3(256), 0, stream>>>(
      W_embed, Wq, Wk, bq, bk_, dq,
      valid_idx, policy_idx, promo_idx, promo_policy_idx, n_valid, n_promo,
      Wt8, Wqk8, dqkp8, uvw_tl, dqc, invP, dflag);

  (void)hipFuncSetAttribute((const void*)dirpolicy_fp8,
                            hipFuncAttributeMaxDynamicSharedMemorySize, LDS_TOTAL);
  if (B > 0)
    dirpolicy_fp8<<<dim3(B), dim3(256), LDS_TOTAL, stream>>>(
        x, b_embed, Wt8, Wqk8, dqkp8, uvw_tl, dqc, invP, d_out, dflag);
}